// Round 14
// baseline (175.567 us; speedup 1.0000x reference)
//
#include <hip/hip_runtime.h>
#include <math.h>

#define B_ 2
#define H_ 8
#define L_ 2048
#define D_ 64
#define BM 16          // rows per WG; all 4 waves share the 16 rows
#define NT 256
#define NBLK 32        // 16-col blocks per wave (wave w owns cols [w*512,(w+1)*512))
#define L2E 1.4426950408889634f

typedef _Float16 half8 __attribute__((ext_vector_type(8)));
typedef __attribute__((ext_vector_type(4))) float f4;

#define MFMA16F(a, b, c) __builtin_amdgcn_mfma_f32_16x16x32_f16(a, b, c, 0, 0, 0)

struct LdsT {
  float muv[2][D_];
  float er0[BM], er1[BM];
  float red[4][BM];
};

__device__ inline half8 cvt8(const float4& a0, const float4& a1) {
  half8 r;
  r[0] = (_Float16)a0.x; r[1] = (_Float16)a0.y;
  r[2] = (_Float16)a0.z; r[3] = (_Float16)a0.w;
  r[4] = (_Float16)a1.x; r[5] = (_Float16)a1.y;
  r[6] = (_Float16)a1.z; r[7] = (_Float16)a1.w;
  return r;
}

// Parallel prep: one thread per (col, 8-dim slot). 1024 WGs.
// wf[((bh*128+blk)*2+hh)*64 + kq*16 + ci] = fp16(k[blk*16+ci][8*(hh*4+kq)..+7])
__global__ __launch_bounds__(256) void prep_kernel(
    const float* __restrict__ k, const float* __restrict__ mask,
    const float* __restrict__ mu, float2* __restrict__ ck,
    half8* __restrict__ wf)
{
  int u   = blockIdx.x * 256 + threadIdx.x;   // 0 .. 262143
  int col = u >> 3;                           // global col 0..32767
  int g   = u & 7;                            // 8-dim slot
  int bh  = col >> 11, c = col & 2047;
  int b   = bh >> 3,   h = bh & 7;
  const float s = -0.0625f;  // -0.5 / sqrt(64)
  const float* kp  = k + (((size_t)bh * L_ + c) * D_) + 8 * g;
  const float* mu0 = mu + (size_t)h * D_ + 8 * g;
  const float* mu1 = mu + (size_t)(H_ * D_) + (size_t)h * D_ + 8 * g;
  float4 x0 = *reinterpret_cast<const float4*>(kp);
  float4 x1 = *reinterpret_cast<const float4*>(kp + 4);
  float xs[8] = {x0.x, x0.y, x0.z, x0.w, x1.x, x1.y, x1.z, x1.w};
  float s0 = 0.f, s1 = 0.f;
#pragma unroll
  for (int i = 0; i < 8; ++i) {
    float a;
    a = xs[i] - mu0[i]; s0 += a * a;
    a = xs[i] - mu1[i]; s1 += a * a;
  }
  // reduce across the 8 lanes of this col (lanes are consecutive, 8-aligned)
  s0 += __shfl_xor(s0, 1, 64); s0 += __shfl_xor(s0, 2, 64); s0 += __shfl_xor(s0, 4, 64);
  s1 += __shfl_xor(s1, 1, 64); s1 += __shfl_xor(s1, 2, 64); s1 += __shfl_xor(s1, 4, 64);
  if (g == 0) {
    float neg = 1.0e6f * (1.0f - mask[(size_t)b * L_ + c]);
    ck[(size_t)bh * L_ + c] = make_float2(exp2f((s * s0 - neg) * L2E),
                                          exp2f((s * s1 - neg) * L2E));
  }
  int blk = c >> 4, ci = c & 15;
  wf[((size_t)bh * 128 + blk) * 128 + (g >> 2) * 64 + (g & 3) * 16 + ci] =
      cvt8(x0, x1);
}

template <bool USE_WS>
__global__ __launch_bounds__(NT, 8) void mg_kernel(
    const float* __restrict__ q, const float* __restrict__ kk,
    const float* __restrict__ mask, const float* __restrict__ mu,
    const float* __restrict__ pi, const float2* __restrict__ ckw,
    const half8* __restrict__ wf, float* __restrict__ out)
{
  __shared__ LdsT S;
  const int t = threadIdx.x;
  int bid = blockIdx.x;
  int vwg = (bid & 7) * 256 + (bid >> 3);   // XCD-chunked, bijective (2048%8==0)
  int bh  = vwg >> 7;
  int rb  = vwg & 127;
  int b = bh >> 3, h = bh & 7;
  int row0 = rb * BM;

  const int w  = t >> 6;   // wave 0..3 -> col range [w*512, w*512+512)
  const int ln = t & 63;
  const int ci = ln & 15;  // col lane / A-row lane
  const int kg = ln >> 4;  // k-slot lane

  const float s   = -0.0625f;
  const float DDC = 0.125f * L2E;   // -2s * log2e

  const float*  maskb = mask + (size_t)b * L_;
  const float2* ckb   = ckw + (size_t)bh * L_;
  const half8*  wfb   = wf + (size_t)bh * (128 * 128);

  if (t < 2 * D_)
    S.muv[t >> 6][t & 63] =
        mu[(size_t)(t >> 6) * (H_ * D_) + (size_t)h * D_ + (t & 63)];

  // A-fragments: 16 Q rows (lane ci = row), k-slots kg and 4+kg
  half8 ah[2];
  {
    const float* qrow = q + ((size_t)bh * L_ + row0 + ci) * D_;
#pragma unroll
    for (int h2 = 0; h2 < 2; ++h2) {
      float4 a0 = *reinterpret_cast<const float4*>(qrow + 32 * h2 + kg * 8);
      float4 a1 = *reinterpret_cast<const float4*>(qrow + 32 * h2 + kg * 8 + 4);
      ah[h2] = cvt8(a0, a1);
    }
  }
  __syncthreads();   // muv visible

  // per-row factors er_c = pi_c * exp2(L2E*(s*q^2 + 2s*(q.mu_c)))
  if (t < BM) {
    float pi0 = fminf(fmaxf(pi[0], 0.f), 1.f);
    float pi1 = fminf(fmaxf(pi[1], 0.f), 1.f);
    const float* qr = q + ((size_t)bh * L_ + row0 + t) * D_;
    float a0 = 0.f, a1 = 0.f, a2 = 0.f;
#pragma unroll
    for (int dq = 0; dq < 16; ++dq) {
      float4 qv = *reinterpret_cast<const float4*>(qr + 4 * dq);
      a0 += qv.x * qv.x + qv.y * qv.y + qv.z * qv.z + qv.w * qv.w;
      a1 += qv.x * S.muv[0][4*dq] + qv.y * S.muv[0][4*dq+1] +
            qv.z * S.muv[0][4*dq+2] + qv.w * S.muv[0][4*dq+3];
      a2 += qv.x * S.muv[1][4*dq] + qv.y * S.muv[1][4*dq+1] +
            qv.z * S.muv[1][4*dq+2] + qv.w * S.muv[1][4*dq+3];
    }
    S.er0[t] = pi0 * exp2f((s * a0 + 2.f * s * a1) * L2E);
    S.er1[t] = pi1 * exp2f((s * a0 + 2.f * s * a2) * L2E);
  }
  __syncthreads();   // er visible

  float e0r[4], e1r[4];
#pragma unroll
  for (int reg = 0; reg < 4; ++reg) {
    e0r[reg] = S.er0[kg * 4 + reg];
    e1r[reg] = S.er1[kg * 4 + reg];
  }

  // load one 16-col block's B-fragments + col factor, straight to registers
  auto LOADCOL = [&](int blk, half8& b0, half8& b1, float2& ec) {
    if (USE_WS) {
      const half8* pb = wfb + (size_t)blk * 128;
      b0 = pb[ln];          // contiguous 1KB wave-load
      b1 = pb[64 + ln];     // contiguous 1KB wave-load
      ec = ckb[blk * 16 + ci];
    } else {
      int col = blk * 16 + ci;
      const float* kp = kk + ((size_t)bh * L_ + col) * D_;
      float4 x0 = *reinterpret_cast<const float4*>(kp + 8 * kg);
      float4 x1 = *reinterpret_cast<const float4*>(kp + 8 * kg + 4);
      float4 x2 = *reinterpret_cast<const float4*>(kp + 32 + 8 * kg);
      float4 x3 = *reinterpret_cast<const float4*>(kp + 32 + 8 * kg + 4);
      b0 = cvt8(x0, x1);
      b1 = cvt8(x2, x3);
      int d0 = 8 * kg, d1 = 32 + 8 * kg;
      float s0 = 0.f, s1 = 0.f;
      float xs[8] = {x0.x, x0.y, x0.z, x0.w, x1.x, x1.y, x1.z, x1.w};
      float ys[8] = {x2.x, x2.y, x2.z, x2.w, x3.x, x3.y, x3.z, x3.w};
#pragma unroll
      for (int i = 0; i < 8; ++i) {
        float a;
        a = xs[i] - S.muv[0][d0 + i]; s0 += a * a;
        a = xs[i] - S.muv[1][d0 + i]; s1 += a * a;
        a = ys[i] - S.muv[0][d1 + i]; s0 += a * a;
        a = ys[i] - S.muv[1][d1 + i]; s1 += a * a;
      }
      s0 += __shfl_xor(s0, 16, 64); s0 += __shfl_xor(s0, 32, 64);
      s1 += __shfl_xor(s1, 16, 64); s1 += __shfl_xor(s1, 32, 64);
      float neg = 1.0e6f * (1.0f - maskb[col]);
      ec = make_float2(exp2f((s * s0 - neg) * L2E),
                       exp2f((s * s1 - neg) * L2E));
    }
  };

  // ---------------- PASS A: row sums (no barriers, prefetched stream) ------
  float rsum[4] = {0.f, 0.f, 0.f, 0.f};
  const int blkw = w * NBLK;
  {
    half8 b0, b1; float2 ec;
    LOADCOL(blkw, b0, b1, ec);
#pragma unroll 2
    for (int j = 0; j < NBLK; ++j) {
      half8 nb0, nb1; float2 nec;
      if (j + 1 < NBLK) LOADCOL(blkw + j + 1, nb0, nb1, nec);  // prefetch
      f4 acc = {0.f, 0.f, 0.f, 0.f};
      acc = MFMA16F(ah[0], b0, acc);
      acc = MFMA16F(ah[1], b1, acc);
#pragma unroll
      for (int reg = 0; reg < 4; ++reg) {
        float g2 = __builtin_amdgcn_exp2f(DDC * acc[reg]);
        float m  = fmaf(e0r[reg], ec.x, e1r[reg] * ec.y);
        rsum[reg] = fmaf(g2, m, rsum[reg]);
      }
      b0 = nb0; b1 = nb1; ec = nec;
    }
  }

  // row-sum reduce: 16 col-lanes, then 4 waves; fold inv into row factors
#pragma unroll
  for (int reg = 0; reg < 4; ++reg) {
    float v = rsum[reg];
    v += __shfl_xor(v, 1, 64);
    v += __shfl_xor(v, 2, 64);
    v += __shfl_xor(v, 4, 64);
    v += __shfl_xor(v, 8, 64);
    if (ci == 0) S.red[w][kg * 4 + reg] = v;
  }
  __syncthreads();
#pragma unroll
  for (int reg = 0; reg < 4; ++reg) {
    int r = kg * 4 + reg;
    float inv = 1.0f / (S.red[0][r] + S.red[1][r] + S.red[2][r] + S.red[3][r]);
    e0r[reg] *= inv;
    e1r[reg] *= inv;
  }

  // ---------------- PASS B: recompute + direct normalized store ------------
  float* ob = out + ((size_t)bh * L_ + row0 + kg * 4) * L_ + w * 512 + ci;
  {
    half8 b0, b1; float2 ec;
    LOADCOL(blkw, b0, b1, ec);
#pragma unroll 2
    for (int j = 0; j < NBLK; ++j) {
      half8 nb0, nb1; float2 nec;
      if (j + 1 < NBLK) LOADCOL(blkw + j + 1, nb0, nb1, nec);  // prefetch
      f4 acc = {0.f, 0.f, 0.f, 0.f};
      acc = MFMA16F(ah[0], b0, acc);
      acc = MFMA16F(ah[1], b1, acc);
#pragma unroll
      for (int reg = 0; reg < 4; ++reg) {
        float g2 = __builtin_amdgcn_exp2f(DDC * acc[reg]);
        float m  = fmaf(e0r[reg], ec.x, e1r[reg] * ec.y);
        float p  = g2 * m;
        __builtin_nontemporal_store(p, ob + (size_t)reg * L_ + j * 16);
      }
      b0 = nb0; b1 = nb1; ec = nec;
    }
  }
}

extern "C" void kernel_launch(void* const* d_in, const int* in_sizes, int n_in,
                              void* d_out, int out_size, void* d_ws, size_t ws_size,
                              hipStream_t stream) {
  const float* q    = (const float*)d_in[0];
  const float* k    = (const float*)d_in[1];
  const float* mask = (const float*)d_in[2];
  const float* mu   = (const float*)d_in[3];
  const float* pi   = (const float*)d_in[4];
  float* out = (float*)d_out;

  const size_t ck_bytes = (size_t)B_ * H_ * L_ * sizeof(float2);       // 256 KB
  const size_t wp_bytes = (size_t)B_ * H_ * L_ * D_ * sizeof(short);   // 4 MB (fp16)
  const bool use_ws = (ws_size >= ck_bytes + wp_bytes) && (d_ws != nullptr);

  if (use_ws) {
    float2* ck = (float2*)d_ws;
    half8*  wf = (half8*)((char*)d_ws + ck_bytes);
    prep_kernel<<<dim3(B_ * H_ * L_ * 8 / 256), dim3(256), 0, stream>>>(
        k, mask, mu, ck, wf);
    mg_kernel<true><<<dim3(B_ * H_ * (L_ / BM)), dim3(NT), 0, stream>>>(
        q, k, mask, mu, pi, ck, wf, out);
  } else {
    mg_kernel<false><<<dim3(B_ * H_ * (L_ / BM)), dim3(NT), 0, stream>>>(
        q, k, mask, mu, pi, nullptr, nullptr, out);
  }
}

// Round 15
// 98.344 us; speedup vs baseline: 1.7852x; 1.7852x over previous
//
#include <hip/hip_runtime.h>
#include <math.h>

#define B_ 2
#define H_ 8
#define L_ 2048
#define D_ 64
#define BM 16          // rows per WG; all 4 waves share the 16 rows
#define NT 256
#define NBLK 32        // 16-col blocks per wave (wave w owns cols [w*512,(w+1)*512))
#define L2E 1.4426950408889634f

typedef _Float16 half8 __attribute__((ext_vector_type(8)));
typedef __attribute__((ext_vector_type(4))) float f4;

#define MFMA16F(a, b, c) __builtin_amdgcn_mfma_f32_16x16x32_f16(a, b, c, 0, 0, 0)

struct LdsT {
  float muv[2][D_];
  float er0[BM], er1[BM];
  float red[4][BM];
};

__device__ inline half8 cvt8(const float4& a0, const float4& a1) {
  half8 r;
  r[0] = (_Float16)a0.x; r[1] = (_Float16)a0.y;
  r[2] = (_Float16)a0.z; r[3] = (_Float16)a0.w;
  r[4] = (_Float16)a1.x; r[5] = (_Float16)a1.y;
  r[6] = (_Float16)a1.z; r[7] = (_Float16)a1.w;
  return r;
}

// Parallel prep (R14-verified): one thread per (col, 8-dim slot). 1024 WGs.
// wf[((bh*128+blk)*2+hh)*64 + kq*16 + ci] = fp16(k[blk*16+ci][8*(hh*4+kq)..+7])
__global__ __launch_bounds__(256) void prep_kernel(
    const float* __restrict__ k, const float* __restrict__ mask,
    const float* __restrict__ mu, float2* __restrict__ ck,
    half8* __restrict__ wf)
{
  int u   = blockIdx.x * 256 + threadIdx.x;   // 0 .. 262143
  int col = u >> 3;                           // global col 0..32767
  int g   = u & 7;                            // 8-dim slot
  int bh  = col >> 11, c = col & 2047;
  int b   = bh >> 3,   h = bh & 7;
  const float s = -0.0625f;  // -0.5 / sqrt(64)
  const float* kp  = k + (((size_t)bh * L_ + c) * D_) + 8 * g;
  const float* mu0 = mu + (size_t)h * D_ + 8 * g;
  const float* mu1 = mu + (size_t)(H_ * D_) + (size_t)h * D_ + 8 * g;
  float4 x0 = *reinterpret_cast<const float4*>(kp);
  float4 x1 = *reinterpret_cast<const float4*>(kp + 4);
  float xs[8] = {x0.x, x0.y, x0.z, x0.w, x1.x, x1.y, x1.z, x1.w};
  float s0 = 0.f, s1 = 0.f;
#pragma unroll
  for (int i = 0; i < 8; ++i) {
    float a;
    a = xs[i] - mu0[i]; s0 += a * a;
    a = xs[i] - mu1[i]; s1 += a * a;
  }
  // reduce across the 8 lanes of this col (lanes consecutive, 8-aligned)
  s0 += __shfl_xor(s0, 1, 64); s0 += __shfl_xor(s0, 2, 64); s0 += __shfl_xor(s0, 4, 64);
  s1 += __shfl_xor(s1, 1, 64); s1 += __shfl_xor(s1, 2, 64); s1 += __shfl_xor(s1, 4, 64);
  if (g == 0) {
    float neg = 1.0e6f * (1.0f - mask[(size_t)b * L_ + c]);
    ck[(size_t)bh * L_ + c] = make_float2(exp2f((s * s0 - neg) * L2E),
                                          exp2f((s * s1 - neg) * L2E));
  }
  int blk = c >> 4, ci = c & 15;
  wf[((size_t)bh * 128 + blk) * 128 + (g >> 2) * 64 + (g & 3) * 16 + ci] =
      cvt8(x0, x1);
}

template <bool USE_WS>
__global__ __launch_bounds__(NT, 8) void mg_kernel(
    const float* __restrict__ q, const float* __restrict__ kk,
    const float* __restrict__ mask, const float* __restrict__ mu,
    const float* __restrict__ pi, const float2* __restrict__ ckw,
    const half8* __restrict__ wf, float* __restrict__ out)
{
  __shared__ LdsT S;
  const int t = threadIdx.x;
  int bid = blockIdx.x;
  int vwg = (bid & 7) * 256 + (bid >> 3);   // XCD-chunked, bijective (2048%8==0)
  int bh  = vwg >> 7;
  int rb  = vwg & 127;
  int b = bh >> 3, h = bh & 7;
  int row0 = rb * BM;

  const int w  = t >> 6;   // wave 0..3 -> col range [w*512, w*512+512)
  const int ln = t & 63;
  const int ci = ln & 15;  // col lane / A-row lane
  const int kg = ln >> 4;  // k-slot lane

  const float s   = -0.0625f;
  const float DDC = 0.125f * L2E;   // -2s * log2e

  const float*  maskb = mask + (size_t)b * L_;
  const float2* ckb   = ckw + (size_t)bh * L_;
  const half8*  wfb   = wf + (size_t)bh * (128 * 128);

  if (t < 2 * D_)
    S.muv[t >> 6][t & 63] =
        mu[(size_t)(t >> 6) * (H_ * D_) + (size_t)h * D_ + (t & 63)];

  // A-fragments: 16 Q rows (lane ci = row), k-slots kg and 4+kg
  half8 ah[2];
  {
    const float* qrow = q + ((size_t)bh * L_ + row0 + ci) * D_;
#pragma unroll
    for (int h2 = 0; h2 < 2; ++h2) {
      float4 a0 = *reinterpret_cast<const float4*>(qrow + 32 * h2 + kg * 8);
      float4 a1 = *reinterpret_cast<const float4*>(qrow + 32 * h2 + kg * 8 + 4);
      ah[h2] = cvt8(a0, a1);
    }
  }
  __syncthreads();   // muv visible

  // per-row factors er_c = pi_c * exp2(L2E*(s*q^2 + 2s*(q.mu_c)))
  if (t < BM) {
    float pi0 = fminf(fmaxf(pi[0], 0.f), 1.f);
    float pi1 = fminf(fmaxf(pi[1], 0.f), 1.f);
    const float* qr = q + ((size_t)bh * L_ + row0 + t) * D_;
    float a0 = 0.f, a1 = 0.f, a2 = 0.f;
#pragma unroll
    for (int dq = 0; dq < 16; ++dq) {
      float4 qv = *reinterpret_cast<const float4*>(qr + 4 * dq);
      a0 += qv.x * qv.x + qv.y * qv.y + qv.z * qv.z + qv.w * qv.w;
      a1 += qv.x * S.muv[0][4*dq] + qv.y * S.muv[0][4*dq+1] +
            qv.z * S.muv[0][4*dq+2] + qv.w * S.muv[0][4*dq+3];
      a2 += qv.x * S.muv[1][4*dq] + qv.y * S.muv[1][4*dq+1] +
            qv.z * S.muv[1][4*dq+2] + qv.w * S.muv[1][4*dq+3];
    }
    S.er0[t] = pi0 * exp2f((s * a0 + 2.f * s * a1) * L2E);
    S.er1[t] = pi1 * exp2f((s * a0 + 2.f * s * a2) * L2E);
  }
  __syncthreads();   // er visible

  float e0r[4], e1r[4];
#pragma unroll
  for (int reg = 0; reg < 4; ++reg) {
    e0r[reg] = S.er0[kg * 4 + reg];
    e1r[reg] = S.er1[kg * 4 + reg];
  }

  // load one 16-col block's B-fragments + col factor, straight to registers
  auto LOADCOL = [&](int blk, half8& b0, half8& b1, float2& ec) {
    if (USE_WS) {
      const half8* pb = wfb + (size_t)blk * 128;
      b0 = pb[ln];          // contiguous 1KB wave-load
      b1 = pb[64 + ln];     // contiguous 1KB wave-load
      ec = ckb[blk * 16 + ci];
    } else {
      int col = blk * 16 + ci;
      const float* kp = kk + ((size_t)bh * L_ + col) * D_;
      float4 x0 = *reinterpret_cast<const float4*>(kp + 8 * kg);
      float4 x1 = *reinterpret_cast<const float4*>(kp + 8 * kg + 4);
      float4 x2 = *reinterpret_cast<const float4*>(kp + 32 + 8 * kg);
      float4 x3 = *reinterpret_cast<const float4*>(kp + 32 + 8 * kg + 4);
      b0 = cvt8(x0, x1);
      b1 = cvt8(x2, x3);
      int d0 = 8 * kg, d1 = 32 + 8 * kg;
      float s0 = 0.f, s1 = 0.f;
      float xs[8] = {x0.x, x0.y, x0.z, x0.w, x1.x, x1.y, x1.z, x1.w};
      float ys[8] = {x2.x, x2.y, x2.z, x2.w, x3.x, x3.y, x3.z, x3.w};
#pragma unroll
      for (int i = 0; i < 8; ++i) {
        float a;
        a = xs[i] - S.muv[0][d0 + i]; s0 += a * a;
        a = xs[i] - S.muv[1][d0 + i]; s1 += a * a;
        a = ys[i] - S.muv[0][d1 + i]; s0 += a * a;
        a = ys[i] - S.muv[1][d1 + i]; s1 += a * a;
      }
      s0 += __shfl_xor(s0, 16, 64); s0 += __shfl_xor(s0, 32, 64);
      s1 += __shfl_xor(s1, 16, 64); s1 += __shfl_xor(s1, 32, 64);
      float neg = 1.0e6f * (1.0f - maskb[col]);
      ec = make_float2(exp2f((s * s0 - neg) * L2E),
                       exp2f((s * s1 - neg) * L2E));
    }
  };

  // ---------------- PASS A: row sums (no barriers, coalesced stream) -------
  float rsum[4] = {0.f, 0.f, 0.f, 0.f};
  const int blkw = w * NBLK;
#pragma unroll 4
  for (int j = 0; j < NBLK; ++j) {
    half8 b0, b1; float2 ec;
    LOADCOL(blkw + j, b0, b1, ec);
    f4 acc = {0.f, 0.f, 0.f, 0.f};
    acc = MFMA16F(ah[0], b0, acc);
    acc = MFMA16F(ah[1], b1, acc);
#pragma unroll
    for (int reg = 0; reg < 4; ++reg) {
      float g2 = __builtin_amdgcn_exp2f(DDC * acc[reg]);
      float m  = fmaf(e0r[reg], ec.x, e1r[reg] * ec.y);
      rsum[reg] = fmaf(g2, m, rsum[reg]);
    }
  }

  // row-sum reduce: 16 col-lanes, then 4 waves; fold inv into row factors
#pragma unroll
  for (int reg = 0; reg < 4; ++reg) {
    float v = rsum[reg];
    v += __shfl_xor(v, 1, 64);
    v += __shfl_xor(v, 2, 64);
    v += __shfl_xor(v, 4, 64);
    v += __shfl_xor(v, 8, 64);
    if (ci == 0) S.red[w][kg * 4 + reg] = v;
  }
  __syncthreads();
#pragma unroll
  for (int reg = 0; reg < 4; ++reg) {
    int r = kg * 4 + reg;
    float inv = 1.0f / (S.red[0][r] + S.red[1][r] + S.red[2][r] + S.red[3][r]);
    e0r[reg] *= inv;
    e1r[reg] *= inv;
  }

  // ---------------- PASS B: recompute + direct normalized store ------------
  float* ob = out + ((size_t)bh * L_ + row0 + kg * 4) * L_ + w * 512 + ci;
#pragma unroll 4
  for (int j = 0; j < NBLK; ++j) {
    half8 b0, b1; float2 ec;
    LOADCOL(blkw + j, b0, b1, ec);
    f4 acc = {0.f, 0.f, 0.f, 0.f};
    acc = MFMA16F(ah[0], b0, acc);
    acc = MFMA16F(ah[1], b1, acc);
#pragma unroll
    for (int reg = 0; reg < 4; ++reg) {
      float g2 = __builtin_amdgcn_exp2f(DDC * acc[reg]);
      float m  = fmaf(e0r[reg], ec.x, e1r[reg] * ec.y);
      float p  = g2 * m;
      __builtin_nontemporal_store(p, ob + (size_t)reg * L_ + j * 16);
    }
  }
}

extern "C" void kernel_launch(void* const* d_in, const int* in_sizes, int n_in,
                              void* d_out, int out_size, void* d_ws, size_t ws_size,
                              hipStream_t stream) {
  const float* q    = (const float*)d_in[0];
  const float* k    = (const float*)d_in[1];
  const float* mask = (const float*)d_in[2];
  const float* mu   = (const float*)d_in[3];
  const float* pi   = (const float*)d_in[4];
  float* out = (float*)d_out;

  const size_t ck_bytes = (size_t)B_ * H_ * L_ * sizeof(float2);       // 256 KB
  const size_t wp_bytes = (size_t)B_ * H_ * L_ * D_ * sizeof(short);   // 4 MB (fp16)
  const bool use_ws = (ws_size >= ck_bytes + wp_bytes) && (d_ws != nullptr);

  if (use_ws) {
    float2* ck = (float2*)d_ws;
    half8*  wf = (half8*)((char*)d_ws + ck_bytes);
    prep_kernel<<<dim3(B_ * H_ * L_ * 8 / 256), dim3(256), 0, stream>>>(
        k, mask, mu, ck, wf);
    mg_kernel<true><<<dim3(B_ * H_ * (L_ / BM)), dim3(NT), 0, stream>>>(
        q, k, mask, mu, pi, ck, wf, out);
  } else {
    mg_kernel<false><<<dim3(B_ * H_ * (L_ / BM)), dim3(NT), 0, stream>>>(
        q, k, mask, mu, pi, nullptr, nullptr, out);
  }
}